// Round 11
// baseline (288.455 us; speedup 1.0000x reference)
//
#include <hip/hip_runtime.h>
#include <hip/hip_bf16.h>
#include <math.h>

#define B_   32
#define L_   512
#define C_   862
#define P_   720
#define H2_  1024
#define M_   (B_*C_)     // 27584 = 64 * 431 exactly
#define PP_  768

typedef __hip_bfloat16 bf16;
typedef __attribute__((ext_vector_type(8))) short s16x8;
typedef __attribute__((ext_vector_type(4))) float f32x4;

__device__ __forceinline__ void gload_lds16(const bf16* g, bf16* lds) {
    __builtin_amdgcn_global_load_lds(
        (const __attribute__((address_space(1))) void*)g,
        (__attribute__((address_space(3))) void*)lds, 16, 0, 0);
}
__device__ __forceinline__ unsigned short f2b(float f) {
    bf16 h = __float2bfloat16(f);
    return *reinterpret_cast<unsigned short*>(&h);
}
__device__ __forceinline__ float b2f(unsigned short u) {
    return __uint_as_float((unsigned int)u << 16);
}

// ---------------------------------------------------------------- DCT matrix (bf16)
__global__ __launch_bounds__(256) void build_dct(bf16* __restrict__ D) {
    int idx = blockIdx.x * 256 + threadIdx.x;
    if (idx >= L_ * L_) return;
    int k = idx >> 9, l = idx & 511;
    double ang = M_PI * (double)((2 * l + 1) * k) / (2.0 * (double)L_);
    D[idx] = __float2bfloat16((float)(2.0 * cos(ang)));
}

__global__ __launch_bounds__(256) void cvt_bf16(const float* __restrict__ in,
                                                bf16* __restrict__ out, int n) {
    int i = blockIdx.x * 256 + threadIdx.x;
    if (i < n) out[i] = __float2bfloat16(in[i]);
}

// Wl (720,512) -> bf16 padded to (768,512) with zeros
__global__ __launch_bounds__(256) void cvt_wl_pad(const float* __restrict__ in,
                                                  bf16* __restrict__ out) {
    int i = blockIdx.x * 256 + threadIdx.x;
    if (i >= PP_ * L_) return;
    int r = i >> 9;
    out[i] = (r < P_) ? __float2bfloat16(in[i]) : __float2bfloat16(0.f);
}

// ---------------------------------------------------- x (B,L,C) -> Xc (B*C,L) bf16
__global__ __launch_bounds__(256) void transpose_x(const float* __restrict__ x,
                                                   bf16* __restrict__ Xc) {
    __shared__ float tile[32][33];
    int b  = blockIdx.z;
    int c0 = blockIdx.x * 32;
    int l0 = blockIdx.y * 32;
    int tx = threadIdx.x & 31, ty = threadIdx.x >> 5;
#pragma unroll
    for (int i = 0; i < 4; ++i) {
        int l = l0 + ty + i * 8, c = c0 + tx;
        float v = 0.f;
        if (l < L_ && c < C_) v = x[((size_t)b * L_ + l) * C_ + c];
        tile[ty + i * 8][tx] = v;
    }
    __syncthreads();
#pragma unroll
    for (int i = 0; i < 4; ++i) {
        int c = c0 + ty + i * 8, l = l0 + tx;
        if (c < C_ && l < L_)
            Xc[((size_t)b * C_ + c) * L_ + l] = __float2bfloat16(tile[tx][ty + i * 8]);
    }
}

// --------------------- row LayerNorm (512), wave-per-row, bf16 in -> bf16 out
template <bool MUL>
__global__ __launch_bounds__(256) void ln_rows(const bf16* __restrict__ X,
                                               const bf16* __restrict__ Xc,
                                               const float* __restrict__ gamma,
                                               const float* __restrict__ beta,
                                               bf16* __restrict__ Out) {
    int row  = blockIdx.x * 4 + (threadIdx.x >> 6);
    int lane = threadIdx.x & 63;
    const s16x8 v = *reinterpret_cast<const s16x8*>(X + (size_t)row * L_ + lane * 8);
    float f[8], s = 0.f, q = 0.f;
#pragma unroll
    for (int e = 0; e < 8; ++e) {
        f[e] = b2f((unsigned short)v[e]);
        s += f[e]; q += f[e] * f[e];
    }
#pragma unroll
    for (int off = 1; off < 64; off <<= 1) {
        s += __shfl_xor(s, off);
        q += __shfl_xor(q, off);
    }
    float mu = s * (1.f / L_);
    float rs = rsqrtf(q * (1.f / L_) - mu * mu + 1e-6f);
    float4 g0 = *reinterpret_cast<const float4*>(gamma + lane * 8);
    float4 g1 = *reinterpret_cast<const float4*>(gamma + lane * 8 + 4);
    float4 b0 = *reinterpret_cast<const float4*>(beta + lane * 8);
    float4 b1 = *reinterpret_cast<const float4*>(beta + lane * 8 + 4);
    float gg[8] = {g0.x, g0.y, g0.z, g0.w, g1.x, g1.y, g1.z, g1.w};
    float bb[8] = {b0.x, b0.y, b0.z, b0.w, b1.x, b1.y, b1.z, b1.w};
    float xm[8];
    if (MUL) {
        const s16x8 xv = *reinterpret_cast<const s16x8*>(Xc + (size_t)row * L_ + lane * 8);
#pragma unroll
        for (int e = 0; e < 8; ++e) xm[e] = b2f((unsigned short)xv[e]);
    }
    s16x8 o;
#pragma unroll
    for (int e = 0; e < 8; ++e) {
        float y = (f[e] - mu) * rs * gg[e] + bb[e];
        if (MUL) y *= xm[e];
        o[e] = (short)f2b(y);
    }
    *reinterpret_cast<s16x8*>(Out + (size_t)row * L_ + lane * 8) = o;
}

// ------------------------------------------------------------------ flat GEMM v2
// Block = 64 M-rows (4 waves x 16). A preloaded ONCE into regs. Weights stream
// through DOUBLE-buffered LDS chunks (BN rows x KT, padded stride KT+8 elems:
// linear DMA source, linear reads, bank group = (row+granule)%8 -> conflict-free).
// Per chunk: prefetch next (DMA) -> compute current (~1400 cy >> L2 latency)
// -> store -> __syncthreads (prefetch already landed).
// Grid (431, NSPLIT): y splits the N-chunks; A re-read per y (cheap, 16.7 MB).
// OUTMODE 0: bf16 linear [m][ldc]; ACT 0 none / 1 relu / 2 sigmoid.
//            acc = mfma(a, bv): m = row0+kq*4+r, n = chunk*BN+jj*16+fr.
// OUTMODE 1: operand-SWAPPED mfma(bv, a): i-dim = weight row p, j-dim = m.
//            Per-lane m = row0+fr -> consecutive c -> COALESCED f32 scatter
//            out[b][p][c] + bias[p], guard p < P_.
template <int KT, int ACT, int OUTMODE>
__global__ __launch_bounds__(256, 2)
void flatmm(const bf16* __restrict__ A, const bf16* __restrict__ Wm,
            const float* __restrict__ bias, void* __restrict__ Out,
            int ldc, int NCper) {
    constexpr int STRIDE = KT + 8;            // padded row stride (elements)
    constexpr int HALVES = KT / 512;          // 1024B DMA segments per row
    constexpr int BN     = 32 / HALVES;       // chunk rows: 32 (K=512) / 16 (K=1024)
    constexpr int TSTEPS = KT / 32;           // MFMA k-steps
    constexpr int NJ     = BN / 16;           // 2 or 1
    __shared__ __align__(16) bf16 Wc[2][BN * STRIDE];   // ~65 KB

    int tid = threadIdx.x, w = tid >> 6, lane = tid & 63;
    int fr = lane & 15, kq = lane >> 4;
    int row0 = blockIdx.x * 64 + w * 16;
    int c0 = blockIdx.y * NCper;

    // ---- A preload: 16 rows x KT, read exactly once per y-split
    s16x8 a[TSTEPS];
    {
        const char* Ar = (const char*)A + (size_t)(row0 + fr) * (KT * 2) + kq * 16;
#pragma unroll
        for (int t = 0; t < TSTEPS; ++t)
            a[t] = *reinterpret_cast<const s16x8*>(Ar + t * 64);
    }

    int mb = 0, mc = 0;
    if (OUTMODE == 1) {
        int m = row0 + fr;
        mb = m / C_; mc = m - mb * C_;
    }

    const char* Wb = (const char*)Wm;

#define STAGEC(bi, c)                                                              \
    do {                                                                           \
        _Pragma("unroll")                                                          \
        for (int i_ = 0; i_ < 8; ++i_) {                                           \
            int s_ = w * 8 + i_;                                                   \
            int r_ = s_ / HALVES, h_ = s_ % HALVES;                                \
            gload_lds16((const bf16*)(Wb + (size_t)((c) * BN + r_) * (KT * 2)      \
                                      + h_ * 1024 + (lane << 4)),                  \
                        &Wc[bi][r_ * STRIDE + h_ * 512]);                          \
        }                                                                          \
    } while (0)

    STAGEC(0, c0);
    __syncthreads();

    int buf = 0;
    for (int cc = 0; cc < NCper; ++cc) {
        if (cc + 1 < NCper) STAGEC(buf ^ 1, c0 + cc + 1);   // prefetch next chunk

        f32x4 acc[NJ] = {};
        const char* Wp = (const char*)&Wc[buf][0];
#pragma unroll
        for (int t = 0; t < TSTEPS; ++t) {
            int g = t * 4 + kq;
            s16x8 bv[NJ];
#pragma unroll
            for (int jj = 0; jj < NJ; ++jj)
                bv[jj] = *reinterpret_cast<const s16x8*>(
                    Wp + (jj * 16 + fr) * (STRIDE * 2) + (g << 4));
#pragma unroll
            for (int jj = 0; jj < NJ; ++jj) {
                if (OUTMODE == 1)
                    acc[jj] = __builtin_amdgcn_mfma_f32_16x16x32_bf16(bv[jj], a[t], acc[jj], 0, 0, 0);
                else
                    acc[jj] = __builtin_amdgcn_mfma_f32_16x16x32_bf16(a[t], bv[jj], acc[jj], 0, 0, 0);
            }
        }

        // ---- epilogue for this chunk
        if (OUTMODE == 0) {
#pragma unroll
            for (int jj = 0; jj < NJ; ++jj) {
                int n = (c0 + cc) * BN + jj * 16 + fr;
#pragma unroll
                for (int r = 0; r < 4; ++r) {
                    int m = row0 + kq * 4 + r;
                    float v = acc[jj][r];
                    if (ACT == 1) v = fmaxf(v, 0.f);
                    if (ACT == 2) v = 1.f / (1.f + __expf(-v));
                    ((bf16*)Out)[(size_t)m * ldc + n] = __float2bfloat16(v);
                }
            }
        } else {
            float* ob = (float*)Out + (size_t)mb * (P_ * C_) + mc;
#pragma unroll
            for (int jj = 0; jj < NJ; ++jj) {
#pragma unroll
                for (int r = 0; r < 4; ++r) {
                    int p = (c0 + cc) * BN + jj * 16 + kq * 4 + r;
                    if (p < P_)
                        ob[(size_t)p * C_] = acc[jj][r] + bias[p];
                }
            }
        }
        __syncthreads();   // prefetch landed long ago; all reads of buf done
        buf ^= 1;
    }
#undef STAGEC
}

extern "C" void kernel_launch(void* const* d_in, const int* in_sizes, int n_in,
                              void* d_out, int out_size, void* d_ws, size_t ws_size,
                              hipStream_t stream) {
    const float* x     = (const float*)d_in[0];
    const float* W1    = (const float*)d_in[1];
    const float* W2    = (const float*)d_in[2];
    const float* gamma = (const float*)d_in[3];
    const float* beta  = (const float*)d_in[4];
    const float* Wl    = (const float*)d_in[5];
    const float* bl    = (const float*)d_in[6];
    float* out = (float*)d_out;

    bf16* ws   = (bf16*)d_ws;
    bf16* Xc   = ws;                           // M_ x 512
    bf16* Fq   = Xc + (size_t)M_ * L_;         // M_ x 512 (freq, later fw)
    bf16* Fn   = Fq + (size_t)M_ * L_;         // M_ x 512 (Fn, later Prod)
    bf16* Hb   = Fn + (size_t)M_ * L_;         // M_ x 1024
    bf16* Dbf  = Hb + (size_t)M_ * H2_;        // 512 x 512
    bf16* W1bf = Dbf + (size_t)L_ * L_;        // 1024 x 512
    bf16* W2bf = W1bf + (size_t)H2_ * L_;      // 512 x 1024
    bf16* Wlbf = W2bf + (size_t)L_ * H2_;      // 768 x 512 (zero-padded)

    build_dct<<<(L_ * L_ + 255) / 256, 256, 0, stream>>>(Dbf);
    cvt_bf16<<<(H2_ * L_ + 255) / 256, 256, 0, stream>>>(W1, W1bf, H2_ * L_);
    cvt_bf16<<<(L_ * H2_ + 255) / 256, 256, 0, stream>>>(W2, W2bf, L_ * H2_);
    cvt_wl_pad<<<(PP_ * L_ + 255) / 256, 256, 0, stream>>>(Wl, Wlbf);
    transpose_x<<<dim3((C_ + 31) / 32, (L_ + 31) / 32, B_), 256, 0, stream>>>(x, Xc);

    // Stage A: freq = Xc . D^T  (bf16), K=512, 16 chunks split over y=2
    flatmm<512, 0, 0><<<dim3(M_ / 64, 2), 256, 0, stream>>>(Xc, Dbf, nullptr, Fq, L_, 8);
    ln_rows<false><<<M_ / 4, 256, 0, stream>>>(Fq, nullptr, gamma, beta, Fn);

    // Stage B: H = relu(Fn . W1^T)  (bf16), K=512, 32 chunks split over y=2
    flatmm<512, 1, 0><<<dim3(M_ / 64, 2), 256, 0, stream>>>(Fn, W1bf, nullptr, Hb, H2_, 16);

    // Stage C: fw = sigmoid(H . W2^T)  (bf16), K=1024 in-register, 32 chunks over y=2
    flatmm<1024, 2, 0><<<dim3(M_ / 64, 2), 256, 0, stream>>>(Hb, W2bf, nullptr, Fq, L_, 16);
    // Prod = LN(fw) * Xc
    ln_rows<true><<<M_ / 4, 256, 0, stream>>>(Fq, Xc, gamma, beta, Fn);

    // Stage D (operand-swapped MFMA -> coalesced scatter): out[b,p,c] += bl[p]
    flatmm<512, 0, 1><<<dim3(M_ / 64, 1), 256, 0, stream>>>(Fn, Wlbf, bl, out, 0, 23);
}

// Round 12
// 277.392 us; speedup vs baseline: 1.0399x; 1.0399x over previous
//
#include <hip/hip_runtime.h>
#include <hip/hip_bf16.h>
#include <math.h>

#define B_   32
#define L_   512
#define C_   862
#define P_   720
#define H2_  1024
#define M_   (B_*C_)     // 27584 = 64 * 431 exactly
#define PP_  768

typedef __hip_bfloat16 bf16;
typedef __attribute__((ext_vector_type(8))) short s16x8;
typedef __attribute__((ext_vector_type(4))) float f32x4;

__device__ __forceinline__ void gload_lds16(const bf16* g, bf16* lds) {
    __builtin_amdgcn_global_load_lds(
        (const __attribute__((address_space(1))) void*)g,
        (__attribute__((address_space(3))) void*)lds, 16, 0, 0);
}
__device__ __forceinline__ unsigned short f2b(float f) {
    bf16 h = __float2bfloat16(f);
    return *reinterpret_cast<unsigned short*>(&h);
}
__device__ __forceinline__ float b2f(unsigned short u) {
    return __uint_as_float((unsigned int)u << 16);
}

// ---------------------------------------------------------------- DCT matrix (bf16)
__global__ __launch_bounds__(256) void build_dct(bf16* __restrict__ D) {
    int idx = blockIdx.x * 256 + threadIdx.x;
    if (idx >= L_ * L_) return;
    int k = idx >> 9, l = idx & 511;
    double ang = M_PI * (double)((2 * l + 1) * k) / (2.0 * (double)L_);
    D[idx] = __float2bfloat16((float)(2.0 * cos(ang)));
}

__global__ __launch_bounds__(256) void cvt_bf16(const float* __restrict__ in,
                                                bf16* __restrict__ out, int n) {
    int i = blockIdx.x * 256 + threadIdx.x;
    if (i < n) out[i] = __float2bfloat16(in[i]);
}

// Wl (720,512) -> bf16 padded to (768,512) with zeros
__global__ __launch_bounds__(256) void cvt_wl_pad(const float* __restrict__ in,
                                                  bf16* __restrict__ out) {
    int i = blockIdx.x * 256 + threadIdx.x;
    if (i >= PP_ * L_) return;
    int r = i >> 9;
    out[i] = (r < P_) ? __float2bfloat16(in[i]) : __float2bfloat16(0.f);
}

// ---------------------------------------------------- x (B,L,C) -> Xc (B*C,L) bf16
__global__ __launch_bounds__(256) void transpose_x(const float* __restrict__ x,
                                                   bf16* __restrict__ Xc) {
    __shared__ float tile[32][33];
    int b  = blockIdx.z;
    int c0 = blockIdx.x * 32;
    int l0 = blockIdx.y * 32;
    int tx = threadIdx.x & 31, ty = threadIdx.x >> 5;
#pragma unroll
    for (int i = 0; i < 4; ++i) {
        int l = l0 + ty + i * 8, c = c0 + tx;
        float v = 0.f;
        if (l < L_ && c < C_) v = x[((size_t)b * L_ + l) * C_ + c];
        tile[ty + i * 8][tx] = v;
    }
    __syncthreads();
#pragma unroll
    for (int i = 0; i < 4; ++i) {
        int c = c0 + ty + i * 8, l = l0 + tx;
        if (c < C_ && l < L_)
            Xc[((size_t)b * C_ + c) * L_ + l] = __float2bfloat16(tile[tx][ty + i * 8]);
    }
}

// --------------------- row LayerNorm (512), wave-per-row, bf16 in -> bf16 out
template <bool MUL>
__global__ __launch_bounds__(256) void ln_rows(const bf16* __restrict__ X,
                                               const bf16* __restrict__ Xc,
                                               const float* __restrict__ gamma,
                                               const float* __restrict__ beta,
                                               bf16* __restrict__ Out) {
    int row  = blockIdx.x * 4 + (threadIdx.x >> 6);
    int lane = threadIdx.x & 63;
    const s16x8 v = *reinterpret_cast<const s16x8*>(X + (size_t)row * L_ + lane * 8);
    float f[8], s = 0.f, q = 0.f;
#pragma unroll
    for (int e = 0; e < 8; ++e) {
        f[e] = b2f((unsigned short)v[e]);
        s += f[e]; q += f[e] * f[e];
    }
#pragma unroll
    for (int off = 1; off < 64; off <<= 1) {
        s += __shfl_xor(s, off);
        q += __shfl_xor(q, off);
    }
    float mu = s * (1.f / L_);
    float rs = rsqrtf(q * (1.f / L_) - mu * mu + 1e-6f);
    float4 g0 = *reinterpret_cast<const float4*>(gamma + lane * 8);
    float4 g1 = *reinterpret_cast<const float4*>(gamma + lane * 8 + 4);
    float4 b0 = *reinterpret_cast<const float4*>(beta + lane * 8);
    float4 b1 = *reinterpret_cast<const float4*>(beta + lane * 8 + 4);
    float gg[8] = {g0.x, g0.y, g0.z, g0.w, g1.x, g1.y, g1.z, g1.w};
    float bb[8] = {b0.x, b0.y, b0.z, b0.w, b1.x, b1.y, b1.z, b1.w};
    float xm[8];
    if (MUL) {
        const s16x8 xv = *reinterpret_cast<const s16x8*>(Xc + (size_t)row * L_ + lane * 8);
#pragma unroll
        for (int e = 0; e < 8; ++e) xm[e] = b2f((unsigned short)xv[e]);
    }
    s16x8 o;
#pragma unroll
    for (int e = 0; e < 8; ++e) {
        float y = (f[e] - mu) * rs * gg[e] + bb[e];
        if (MUL) y *= xm[e];
        o[e] = (short)f2b(y);
    }
    *reinterpret_cast<s16x8*>(Out + (size_t)row * L_ + lane * 8) = o;
}

// ------------------------------------------------------------------ flat GEMM v3
// Identical to v2 except: PER-BLOCK CHUNK ROTATION (anti-hot-spot). All blocks
// previously streamed the SAME 32 KB weight chunk simultaneously -> that window
// maps to few L2 slices -> 256 CUs serialize on them. Rotating the chunk order
// by blockIdx.x spreads concurrent reads across the whole weight matrix.
// Chunk order is commutative: acc is per-chunk, epilogue indexed by actual c.
template <int KT, int ACT, int OUTMODE>
__global__ __launch_bounds__(256, 2)
void flatmm(const bf16* __restrict__ A, const bf16* __restrict__ Wm,
            const float* __restrict__ bias, void* __restrict__ Out,
            int ldc, int NCper) {
    constexpr int STRIDE = KT + 8;            // padded row stride (elements)
    constexpr int HALVES = KT / 512;          // 1024B DMA segments per row
    constexpr int BN     = 32 / HALVES;       // chunk rows: 32 (K=512) / 16 (K=1024)
    constexpr int TSTEPS = KT / 32;           // MFMA k-steps
    constexpr int NJ     = BN / 16;           // 2 or 1
    __shared__ __align__(16) bf16 Wc[2][BN * STRIDE];   // ~65 KB

    int tid = threadIdx.x, w = tid >> 6, lane = tid & 63;
    int fr = lane & 15, kq = lane >> 4;
    int row0 = blockIdx.x * 64 + w * 16;
    int c0 = blockIdx.y * NCper;
    int rot = blockIdx.x % NCper;             // per-block rotation offset

    // ---- A preload: 16 rows x KT, read exactly once per y-split
    s16x8 a[TSTEPS];
    {
        const char* Ar = (const char*)A + (size_t)(row0 + fr) * (KT * 2) + kq * 16;
#pragma unroll
        for (int t = 0; t < TSTEPS; ++t)
            a[t] = *reinterpret_cast<const s16x8*>(Ar + t * 64);
    }

    int mb = 0, mc = 0;
    if (OUTMODE == 1) {
        int m = row0 + fr;
        mb = m / C_; mc = m - mb * C_;
    }

    const char* Wb = (const char*)Wm;

#define STAGEC(bi, c)                                                              \
    do {                                                                           \
        _Pragma("unroll")                                                          \
        for (int i_ = 0; i_ < 8; ++i_) {                                           \
            int s_ = w * 8 + i_;                                                   \
            int r_ = s_ / HALVES, h_ = s_ % HALVES;                                \
            gload_lds16((const bf16*)(Wb + (size_t)((c) * BN + r_) * (KT * 2)      \
                                      + h_ * 1024 + (lane << 4)),                  \
                        &Wc[bi][r_ * STRIDE + h_ * 512]);                          \
        }                                                                          \
    } while (0)

    int cprev = c0 + rot;
    STAGEC(0, cprev);
    __syncthreads();

    int buf = 0;
    for (int cc = 0; cc < NCper; ++cc) {
        int ccur = cprev;
        if (cc + 1 < NCper) {
            int cn = cc + 1 + rot;
            if (cn >= NCper) cn -= NCper;
            cprev = c0 + cn;
            STAGEC(buf ^ 1, cprev);              // prefetch next (rotated) chunk
        }

        f32x4 acc[NJ] = {};
        const char* Wp = (const char*)&Wc[buf][0];
#pragma unroll
        for (int t = 0; t < TSTEPS; ++t) {
            int g = t * 4 + kq;
            s16x8 bv[NJ];
#pragma unroll
            for (int jj = 0; jj < NJ; ++jj)
                bv[jj] = *reinterpret_cast<const s16x8*>(
                    Wp + (jj * 16 + fr) * (STRIDE * 2) + (g << 4));
#pragma unroll
            for (int jj = 0; jj < NJ; ++jj) {
                if (OUTMODE == 1)
                    acc[jj] = __builtin_amdgcn_mfma_f32_16x16x32_bf16(bv[jj], a[t], acc[jj], 0, 0, 0);
                else
                    acc[jj] = __builtin_amdgcn_mfma_f32_16x16x32_bf16(a[t], bv[jj], acc[jj], 0, 0, 0);
            }
        }

        // ---- epilogue for this chunk (indexed by ACTUAL chunk ccur)
        if (OUTMODE == 0) {
#pragma unroll
            for (int jj = 0; jj < NJ; ++jj) {
                int n = ccur * BN + jj * 16 + fr;
#pragma unroll
                for (int r = 0; r < 4; ++r) {
                    int m = row0 + kq * 4 + r;
                    float v = acc[jj][r];
                    if (ACT == 1) v = fmaxf(v, 0.f);
                    if (ACT == 2) v = 1.f / (1.f + __expf(-v));
                    ((bf16*)Out)[(size_t)m * ldc + n] = __float2bfloat16(v);
                }
            }
        } else {
            float* ob = (float*)Out + (size_t)mb * (P_ * C_) + mc;
#pragma unroll
            for (int jj = 0; jj < NJ; ++jj) {
#pragma unroll
                for (int r = 0; r < 4; ++r) {
                    int p = ccur * BN + jj * 16 + kq * 4 + r;
                    if (p < P_)
                        ob[(size_t)p * C_] = acc[jj][r] + bias[p];
                }
            }
        }
        __syncthreads();   // prefetch landed; all reads of buf done
        buf ^= 1;
    }
#undef STAGEC
}

extern "C" void kernel_launch(void* const* d_in, const int* in_sizes, int n_in,
                              void* d_out, int out_size, void* d_ws, size_t ws_size,
                              hipStream_t stream) {
    const float* x     = (const float*)d_in[0];
    const float* W1    = (const float*)d_in[1];
    const float* W2    = (const float*)d_in[2];
    const float* gamma = (const float*)d_in[3];
    const float* beta  = (const float*)d_in[4];
    const float* Wl    = (const float*)d_in[5];
    const float* bl    = (const float*)d_in[6];
    float* out = (float*)d_out;

    bf16* ws   = (bf16*)d_ws;
    bf16* Xc   = ws;                           // M_ x 512
    bf16* Fq   = Xc + (size_t)M_ * L_;         // M_ x 512 (freq, later fw)
    bf16* Fn   = Fq + (size_t)M_ * L_;         // M_ x 512 (Fn, later Prod)
    bf16* Hb   = Fn + (size_t)M_ * L_;         // M_ x 1024
    bf16* Dbf  = Hb + (size_t)M_ * H2_;        // 512 x 512
    bf16* W1bf = Dbf + (size_t)L_ * L_;        // 1024 x 512
    bf16* W2bf = W1bf + (size_t)H2_ * L_;      // 512 x 1024
    bf16* Wlbf = W2bf + (size_t)L_ * H2_;      // 768 x 512 (zero-padded)

    build_dct<<<(L_ * L_ + 255) / 256, 256, 0, stream>>>(Dbf);
    cvt_bf16<<<(H2_ * L_ + 255) / 256, 256, 0, stream>>>(W1, W1bf, H2_ * L_);
    cvt_bf16<<<(L_ * H2_ + 255) / 256, 256, 0, stream>>>(W2, W2bf, L_ * H2_);
    cvt_wl_pad<<<(PP_ * L_ + 255) / 256, 256, 0, stream>>>(Wl, Wlbf);
    transpose_x<<<dim3((C_ + 31) / 32, (L_ + 31) / 32, B_), 256, 0, stream>>>(x, Xc);

    // Stage A: freq = Xc . D^T  (bf16), K=512, 16 chunks split over y=2
    flatmm<512, 0, 0><<<dim3(M_ / 64, 2), 256, 0, stream>>>(Xc, Dbf, nullptr, Fq, L_, 8);
    ln_rows<false><<<M_ / 4, 256, 0, stream>>>(Fq, nullptr, gamma, beta, Fn);

    // Stage B: H = relu(Fn . W1^T)  (bf16), K=512, 32 chunks split over y=2
    flatmm<512, 1, 0><<<dim3(M_ / 64, 2), 256, 0, stream>>>(Fn, W1bf, nullptr, Hb, H2_, 16);

    // Stage C: fw = sigmoid(H . W2^T)  (bf16), K=1024 in-register, 32 chunks over y=2
    flatmm<1024, 2, 0><<<dim3(M_ / 64, 2), 256, 0, stream>>>(Hb, W2bf, nullptr, Fq, L_, 16);
    // Prod = LN(fw) * Xc
    ln_rows<true><<<M_ / 4, 256, 0, stream>>>(Fq, Xc, gamma, beta, Fn);

    // Stage D (operand-swapped MFMA -> coalesced scatter): out[b,p,c] += bl[p]
    flatmm<512, 0, 1><<<dim3(M_ / 64, 1), 256, 0, stream>>>(Fn, Wlbf, bl, out, 0, 23);
}